// Round 2
// baseline (95613.605 us; speedup 1.0000x reference)
//
#include <hip/hip_runtime.h>
#include <cstdint>

#define Bb 32
#define Cc 512
#define Nn 384
#define Vv 600
#define Ee 256
#define Dd 512
#define Tt 192
#define Ss 191
#define EOS_TOK 130
#define BD (Bb*Dd)          // 16384
#define G4 2048             // 4*D
#define KREC 1280           // E + D + D
#define KSPLIT 8
#define KCH 160             // KREC/KSPLIT
#define NB 256

// ---- ws layout (float offsets) ----
#define OFF_TOK   0
#define OFF_PART  8192                       // KSPLIT*Bb*G4 = 524288
#define OFF_QPART OFF_PART                   // alias (time-disjoint)
#define OFF_OPART (OFF_PART + 262144)        // alias (time-disjoint)
#define OFF_WV    (OFF_PART + 524288)        // Bb*Nn*Dd = 6291456
#define OFF_HX    (OFF_WV + 6291456)
#define OFF_CX    (OFF_HX + 16384)
#define OFF_Q     (OFF_CX + 16384)
#define OFF_CTX   (OFF_Q + 16384)
#define OFF_SC    (OFF_CTX + 16384)
#define OFF_OBUF  (OFF_SC + 16384)           // 192*BD = 3145728
#define OFF_BAR   (OFF_OBUF + 192*16384)     // 1024 ints

#define LOGITS_SZ (Bb*Ss*Vv)  // 3667200

__device__ __forceinline__ float sigm_(float x) {
    float e = __expf(-x);
    return __builtin_amdgcn_rcpf(1.0f + e);
}
__device__ __forceinline__ float tanh_(float x) {
    float xc = fminf(15.0f, fmaxf(-15.0f, x));
    float e = __expf(2.0f * xc);
    return (e - 1.0f) * __builtin_amdgcn_rcpf(e + 1.0f);
}

// Device-wide tree barrier. Monotonic counters (no reset), generation flag.
// bar[g*64] leaf counters (8 groups of 32 blocks), bar[512] root, bar[576] gen.
__device__ __forceinline__ void gbar(int* bar, int ibar) {
    __threadfence();
    __syncthreads();
    if (threadIdx.x == 0) {
        int g = blockIdx.x >> 5;
        int a = __hip_atomic_fetch_add(&bar[g * 64], 1, __ATOMIC_ACQ_REL,
                                       __HIP_MEMORY_SCOPE_AGENT);
        if (a == ibar * 32 + 31) {
            int r = __hip_atomic_fetch_add(&bar[512], 1, __ATOMIC_ACQ_REL,
                                           __HIP_MEMORY_SCOPE_AGENT);
            if (r == ibar * 8 + 7) {
                __hip_atomic_store(&bar[576], ibar + 1, __ATOMIC_RELEASE,
                                   __HIP_MEMORY_SCOPE_AGENT);
            } else {
                while (__hip_atomic_load(&bar[576], __ATOMIC_ACQUIRE,
                                         __HIP_MEMORY_SCOPE_AGENT) <= ibar)
                    __builtin_amdgcn_s_sleep(2);
            }
        } else {
            while (__hip_atomic_load(&bar[576], __ATOMIC_ACQUIRE,
                                     __HIP_MEMORY_SCOPE_AGENT) <= ibar)
                __builtin_amdgcn_s_sleep(2);
        }
    }
    __syncthreads();
    __threadfence();
}

// S0: zero state, barrier counters, and precompute token sequence.
__global__ void k_setup(const int* __restrict__ tgt, float* hx, float* cx,
                        float* obuf0, int* tok, int* bar) {
    int idx = blockIdx.x * 256 + threadIdx.x;
    if (idx < BD) { hx[idx] = 0.f; cx[idx] = 0.f; obuf0[idx] = 0.f; }
    if (blockIdx.x == 0) {
        for (int i = 0; i < 4; ++i) bar[threadIdx.x + i * 256] = 0;
        __shared__ int is64;
        if (threadIdx.x == 0) {
            int a = 1;
            for (int k = 0; k < 32; ++k) if (tgt[2 * k + 1] != 0) a = 0;
            is64 = a;
        }
        __syncthreads();
        int b = threadIdx.x;
        if (b < Bb) {
            int fin = 0;
            tok[0 * Bb + b] = 0;
            for (int s = 1; s < Ss; ++s) {
                int li = b * Tt + s;
                int nt = is64 ? tgt[2 * li] : tgt[li];
                if (nt == EOS_TOK) fin = 1;
                tok[s * Bb + b] = fin ? 0 : nt;
            }
        }
    }
}

// S1: Wv[b,n,d] = sum_c enc[b,n,c] * W_v[c,d]
__global__ void k_wv(const float* __restrict__ enc, const float* __restrict__ Wv_w,
                     float* __restrict__ Wv) {
    int b = blockIdx.x / 24, nt = blockIdx.x % 24, n0 = nt * 16;
    __shared__ float encL[16 * 512];
    for (int i = 0; i < 32; ++i) {
        int e = threadIdx.x + i * 256;
        int ni = e >> 9, c = e & 511;
        encL[e] = enc[((b * Nn) + (n0 + ni)) * Cc + c];
    }
    __syncthreads();
    int d0 = threadIdx.x, d1 = threadIdx.x + 256;
    float a0[16], a1[16];
#pragma unroll
    for (int i = 0; i < 16; ++i) { a0[i] = 0.f; a1[i] = 0.f; }
    for (int c = 0; c < 512; ++c) {
        float w0 = Wv_w[c * Dd + d0], w1 = Wv_w[c * Dd + d1];
#pragma unroll
        for (int i = 0; i < 16; ++i) {
            float ev = encL[i * 512 + c];
            a0[i] += ev * w0; a1[i] += ev * w1;
        }
    }
#pragma unroll
    for (int i = 0; i < 16; ++i) {
        Wv[((b * Nn) + (n0 + i)) * Dd + d0] = a0[i];
        Wv[((b * Nn) + (n0 + i)) * Dd + d1] = a1[i];
    }
}

// Persistent decode loop: 191 steps, 8 phases/step, device barriers between.
__global__ __launch_bounds__(256, 1) void k_decode(
    const float* __restrict__ enc, const float* __restrict__ emb,
    const float* __restrict__ W_ih, const float* __restrict__ b_ih,
    const float* __restrict__ W_hh, const float* __restrict__ b_hh,
    const float* __restrict__ W_h, const float* __restrict__ vv,
    const float* __restrict__ W_c, const float* __restrict__ b_c,
    const int* __restrict__ tok, const float* __restrict__ Wv,
    float* __restrict__ part, float* __restrict__ qpart, float* __restrict__ opart,
    float* __restrict__ hx, float* __restrict__ cx, float* __restrict__ q,
    float* __restrict__ ctx, float* __restrict__ sc, float* __restrict__ obuf,
    float* __restrict__ out_alphas, int* bar)
{
    __shared__ float smem[5120];
    const int bid = blockIdx.x, tid = threadIdx.x;
    const int lane = tid & 63;
    int ib = 0;

    for (int t = 0; t < Ss; ++t) {
        // ---------- Phase A: gates partials (jt = bid&31 over 64 j, ks = bid>>5) ----------
        {
            const float* o_prev = obuf + (size_t)t * BD;
            int jt = bid & 31, ks = bid >> 5;
            int j0 = jt * 64;
            for (int i = 0; i < 20; ++i) {
                int e = tid + i * 256;
                int b = e / KCH, k = e - b * KCH;
                int kg = ks * KCH + k;
                float val;
                if (kg < Ee)            val = emb[tok[t * Bb + b] * Ee + kg];
                else if (kg < Ee + Dd)  val = o_prev[b * Dd + (kg - Ee)];
                else                    val = hx[b * Dd + (kg - Ee - Dd)];
                smem[k * 32 + b] = val;
            }
            __syncthreads();
            int jl = tid & 63, bg = tid >> 6;
            int j = j0 + jl;
            float acc[8];
#pragma unroll
            for (int i = 0; i < 8; ++i) acc[i] = 0.f;
            for (int k = 0; k < KCH; ++k) {
                int kg = ks * KCH + k;
                const float* wrow = (kg < Ee + Dd) ? (W_ih + (size_t)kg * G4)
                                                   : (W_hh + (size_t)(kg - Ee - Dd) * G4);
                float w = wrow[j];
                float4 xa = *(const float4*)&smem[k * 32 + bg * 8];
                float4 xb = *(const float4*)&smem[k * 32 + bg * 8 + 4];
                acc[0] += xa.x * w; acc[1] += xa.y * w; acc[2] += xa.z * w; acc[3] += xa.w * w;
                acc[4] += xb.x * w; acc[5] += xb.y * w; acc[6] += xb.z * w; acc[7] += xb.w * w;
            }
#pragma unroll
            for (int i = 0; i < 8; ++i)
                part[ks * (Bb * G4) + (bg * 8 + i) * G4 + j] = acc[i];
        }
        gbar(bar, ib++);

        // ---------- Phase B: LSTM pointwise + zero ctx ----------
        if (tid < 64) {
            int idx = bid * 64 + tid;
            int b = idx >> 9, d = idx & 511;
            float g[4];
#pragma unroll
            for (int gi = 0; gi < 4; ++gi) {
                int j = gi * Dd + d;
                float s = b_ih[j] + b_hh[j];
#pragma unroll
                for (int ks = 0; ks < KSPLIT; ++ks)
                    s += part[ks * (Bb * G4) + b * G4 + j];
                g[gi] = s;
            }
            float i_ = sigm_(g[0]), f_ = sigm_(g[1]), gg = tanh_(g[2]), oo = sigm_(g[3]);
            float c = f_ * cx[idx] + i_ * gg;
            cx[idx] = c;
            hx[idx] = oo * tanh_(c);
            ctx[idx] = 0.f;
        }
        gbar(bar, ib++);

        // ---------- Phase C1: q partials (dt 16 x kt 16, all 32 b per block) ----------
        {
            float* WL  = smem;          // 32 x (32 pad 36)
            float* hxL = smem + 1152;   // 32 x (32 pad 36)
            int kt = bid & 15, dt = bid >> 4;
            int k0 = kt * 32, d0 = dt * 32;
            {
                int r = tid >> 3, c4 = (tid & 7) * 4;
                *(float4*)&WL[r * 36 + c4]  = *(const float4*)&W_h[(size_t)(k0 + r) * Dd + d0 + c4];
                *(float4*)&hxL[r * 36 + c4] = *(const float4*)&hx[r * Dd + k0 + c4];
            }
            __syncthreads();
            int bb = tid >> 3, dl4 = (tid & 7) * 4;
            float4 acc = {0.f, 0.f, 0.f, 0.f};
            for (int k = 0; k < 32; ++k) {
                float h = hxL[bb * 36 + k];
                float4 w = *(const float4*)&WL[k * 36 + dl4];
                acc.x += h * w.x; acc.y += h * w.y; acc.z += h * w.z; acc.w += h * w.w;
            }
            *(float4*)&qpart[kt * 16384 + bb * 512 + d0 + dl4] = acc;
        }
        gbar(bar, ib++);

        // ---------- Phase C2: q reduce ----------
        if (tid < 64) {
            int idx = bid * 64 + tid;
            float s = 0.f;
#pragma unroll
            for (int kt = 0; kt < 16; ++kt) s += qpart[kt * 16384 + idx];
            q[idx] = s;
        }
        gbar(bar, ib++);

        // ---------- Phase D: scores (1024 waves x 12 (b,n) pairs) ----------
        {
            int w = bid * 4 + (tid >> 6);
            float4 v0 = *(const float4*)&vv[lane * 4];
            float4 v1 = *(const float4*)&vv[256 + lane * 4];
#pragma unroll
            for (int r = 0; r < 12; ++r) {
                int p = w * 12 + r;
                int b = p / 384;
                const float* wvp = Wv + (size_t)p * Dd;
                const float* qb = q + b * Dd;
                float4 wa = *(const float4*)&wvp[lane * 4];
                float4 wb = *(const float4*)&wvp[256 + lane * 4];
                float4 qa = *(const float4*)&qb[lane * 4];
                float4 qc = *(const float4*)&qb[256 + lane * 4];
                float a = v0.x * tanh_(qa.x + wa.x) + v0.y * tanh_(qa.y + wa.y)
                        + v0.z * tanh_(qa.z + wa.z) + v0.w * tanh_(qa.w + wa.w)
                        + v1.x * tanh_(qc.x + wb.x) + v1.y * tanh_(qc.y + wb.y)
                        + v1.z * tanh_(qc.z + wb.z) + v1.w * tanh_(qc.w + wb.w);
#pragma unroll
                for (int off = 32; off > 0; off >>= 1)
                    a += __shfl_down(a, off, 64);
                if (lane == 0) sc[p] = a;
            }
        }
        gbar(bar, ib++);

        // ---------- Phase E: softmax + alpha out + ctx atomics ----------
        {
            float* eL  = smem;          // 384
            float* red = smem + 384;    // 256
            float* aL  = smem + 640;    // 48
            int b = bid >> 3, sl = bid & 7;
            float m = -1e30f;
            for (int n = tid; n < Nn; n += 256) m = fmaxf(m, sc[b * Nn + n]);
            red[tid] = m; __syncthreads();
            for (int s = 128; s > 0; s >>= 1) {
                if (tid < s) red[tid] = fmaxf(red[tid], red[tid + s]);
                __syncthreads();
            }
            m = red[0]; __syncthreads();
            float ps = 0.f;
            for (int n = tid; n < Nn; n += 256) {
                float e = __expf(sc[b * Nn + n] - m);
                eL[n] = e; ps += e;
            }
            red[tid] = ps; __syncthreads();
            for (int s = 128; s > 0; s >>= 1) {
                if (tid < s) red[tid] += red[tid + s];
                __syncthreads();
            }
            float inv = 1.0f / red[0];
            int n0 = sl * 48;
            if (tid < 48) {
                float a = eL[n0 + tid] * inv;
                aL[tid] = a;
                out_alphas[b * (Ss * Nn) + t * Nn + n0 + tid] = a;
            }
            __syncthreads();
            int c0 = tid, c1 = tid + 256;
            float acc0 = 0.f, acc1 = 0.f;
            for (int i = 0; i < 48; ++i) {
                float a = aL[i];
                const float* er = enc + (size_t)((b * Nn) + (n0 + i)) * Cc;
                acc0 += a * er[c0];
                acc1 += a * er[c1];
            }
            atomicAdd(&ctx[b * Cc + c0], acc0);
            atomicAdd(&ctx[b * Cc + c1], acc1);
        }
        gbar(bar, ib++);

        // ---------- Phase F1: o_t partials (dt 16 x kt 16 over 1024 k, all b) ----------
        {
            float* WL = smem;           // 64 x (32 pad 36) = 2304
            float* xL = smem + 2304;    // 32 x (64 pad 68) = 2176
            int kt = bid & 15, dt = bid >> 4;
            int k0 = kt * 64, d0 = dt * 32;
            for (int e = tid; e < 512; e += 256) {
                int r = e >> 3, c4 = (e & 7) * 4;
                *(float4*)&WL[r * 36 + c4] = *(const float4*)&W_c[(size_t)(k0 + r) * Dd + d0 + c4];
            }
            const float* xsrc = (k0 < 512) ? (hx + k0) : (ctx + (k0 - 512));
            for (int e = tid; e < 512; e += 256) {
                int b = e >> 4, k4 = (e & 15) * 4;
                *(float4*)&xL[b * 68 + k4] = *(const float4*)&xsrc[b * 512 + k4];
            }
            __syncthreads();
            int bb = tid >> 3, dl4 = (tid & 7) * 4;
            float4 acc = {0.f, 0.f, 0.f, 0.f};
            for (int k = 0; k < 64; ++k) {
                float x = xL[bb * 68 + k];
                float4 w = *(const float4*)&WL[k * 36 + dl4];
                acc.x += x * w.x; acc.y += x * w.y; acc.z += x * w.z; acc.w += x * w.w;
            }
            *(float4*)&opart[kt * 16384 + bb * 512 + d0 + dl4] = acc;
        }
        gbar(bar, ib++);

        // ---------- Phase F2: o reduce + tanh -> obuf[t+1] ----------
        if (tid < 64) {
            int idx = bid * 64 + tid;
            int d = idx & 511;
            float s = b_c[d];
#pragma unroll
            for (int kt = 0; kt < 16; ++kt) s += opart[kt * 16384 + idx];
            obuf[(size_t)(t + 1) * BD + idx] = tanh_(s);
        }
        gbar(bar, ib++);
    }
}

// Deferred logits GEMM.
__global__ void k_logits(const float* __restrict__ obuf, const float* __restrict__ W_out,
                         const float* __restrict__ b_out, float* __restrict__ out_logits) {
    int b = blockIdx.x / 24, tt = blockIdx.x % 24;
    int t0 = tt * 8;
    int tmax = min(8, Ss - t0);
    __shared__ float oL[8 * 512];
    int tid = threadIdx.x;
    for (int i = 0; i < 16; ++i) {
        int e = tid + i * 256;
        int ti = e >> 9, d = e & 511;
        oL[e] = (ti < tmax) ? obuf[(size_t)(t0 + ti + 1) * BD + b * Dd + d] : 0.f;
    }
    __syncthreads();
    int v0 = tid, v1 = tid + 256, v2 = tid + 512;
    bool h2 = (v2 < Vv);
    int v2c = h2 ? v2 : 0;
    float acc[3][8];
#pragma unroll
    for (int s = 0; s < 3; ++s)
#pragma unroll
        for (int ti = 0; ti < 8; ++ti) acc[s][ti] = 0.f;
    for (int d = 0; d < 512; ++d) {
        float w0 = W_out[d * Vv + v0];
        float w1 = W_out[d * Vv + v1];
        float w2 = W_out[d * Vv + v2c];
#pragma unroll
        for (int ti = 0; ti < 8; ++ti) {
            float o = oL[ti * 512 + d];
            acc[0][ti] += o * w0; acc[1][ti] += o * w1; acc[2][ti] += o * w2;
        }
    }
    for (int ti = 0; ti < tmax; ++ti) {
        size_t base = (size_t)b * (Ss * Vv) + (size_t)(t0 + ti) * Vv;
        out_logits[base + v0] = acc[0][ti] + b_out[v0];
        out_logits[base + v1] = acc[1][ti] + b_out[v1];
        if (h2) out_logits[base + v2] = acc[2][ti] + b_out[v2];
    }
}

extern "C" void kernel_launch(void* const* d_in, const int* in_sizes, int n_in,
                              void* d_out, int out_size, void* d_ws, size_t ws_size,
                              hipStream_t stream) {
    const float* enc   = (const float*)d_in[0];
    const int*   tgt   = (const int*)d_in[1];
    const float* emb   = (const float*)d_in[2];
    const float* W_ih  = (const float*)d_in[3];
    const float* b_ih  = (const float*)d_in[4];
    const float* W_hh  = (const float*)d_in[5];
    const float* b_hh  = (const float*)d_in[6];
    const float* W_h   = (const float*)d_in[7];
    const float* W_v   = (const float*)d_in[8];
    const float* vv    = (const float*)d_in[9];
    const float* W_c   = (const float*)d_in[10];
    const float* b_c   = (const float*)d_in[11];
    const float* W_out = (const float*)d_in[12];
    const float* b_out = (const float*)d_in[13];

    float* wsf   = (float*)d_ws;
    int*   tok   = (int*)d_ws;
    float* part  = wsf + OFF_PART;
    float* qpart = wsf + OFF_QPART;
    float* opart = wsf + OFF_OPART;
    float* Wv    = wsf + OFF_WV;
    float* hx    = wsf + OFF_HX;
    float* cx    = wsf + OFF_CX;
    float* q     = wsf + OFF_Q;
    float* ctx   = wsf + OFF_CTX;
    float* sc    = wsf + OFF_SC;
    float* obuf  = wsf + OFF_OBUF;
    int*   bar   = (int*)(wsf + OFF_BAR);

    float* out_logits = (float*)d_out;
    float* out_alphas = (float*)d_out + LOGITS_SZ;

    k_setup<<<64, 256, 0, stream>>>(tgt, hx, cx, obuf, tok, bar);
    k_wv<<<768, 256, 0, stream>>>(enc, W_v, Wv);
    k_decode<<<NB, 256, 0, stream>>>(enc, emb, W_ih, b_ih, W_hh, b_hh, W_h, vv,
                                     W_c, b_c, tok, Wv, part, qpart, opart,
                                     hx, cx, q, ctx, sc, obuf, out_alphas, bar);
    k_logits<<<768, 256, 0, stream>>>(obuf, W_out, b_out, out_logits);
}

// Round 3
// 25834.113 us; speedup vs baseline: 3.7011x; 3.7011x over previous
//
#include <hip/hip_runtime.h>
#include <cstdint>

#define Bb 32
#define Cc 512
#define Nn 384
#define Vv 600
#define Ee 256
#define Dd 512
#define Tt 192
#define Ss 191
#define EOS_TOK 130
#define BD (Bb*Dd)          // 16384
#define G4 2048             // 4*D
#define KREC 1280           // E + D + D
#define KSPLIT 8
#define KCH 160             // KREC/KSPLIT
#define NB 256

// ---- ws layout (float offsets) ----
#define OFF_TOK   0
#define OFF_PART  8192                       // KSPLIT*Bb*G4 = 524288
#define OFF_QPART OFF_PART                   // alias (time-disjoint)
#define OFF_OPART (OFF_PART + 262144)        // alias (time-disjoint)
#define OFF_WV    (OFF_PART + 524288)        // Bb*Nn*Dd = 6291456
#define OFF_HX    (OFF_WV + 6291456)
#define OFF_CX    (OFF_HX + 16384)
#define OFF_Q     (OFF_CX + 16384)
#define OFF_CTX   (OFF_Q + 16384)
#define OFF_SC    (OFF_CTX + 16384)
#define OFF_OBUF  (OFF_SC + 16384)           // 192*BD = 3145728
#define OFF_BAR   (OFF_OBUF + 192*16384)     // 1024 ints

#define LOGITS_SZ (Bb*Ss*Vv)  // 3667200

__device__ __forceinline__ float sigm_(float x) {
    float e = __expf(-x);
    return __builtin_amdgcn_rcpf(1.0f + e);
}
__device__ __forceinline__ float tanh_(float x) {
    float xc = fminf(15.0f, fmaxf(-15.0f, x));
    float e = __expf(2.0f * xc);
    return (e - 1.0f) * __builtin_amdgcn_rcpf(e + 1.0f);
}

// Device-wide tree barrier, __ockl_grid_sync style:
//   - arrival: RELEASE fetch_add (one buffer_wbl2 per block — flushes this
//     XCD's dirty L2 so other XCDs can see our phase writes at LLC)
//   - spin: RELAXED atomic load (sc1 LLC read, NO cache invalidate per iter —
//     round 2 used ACQUIRE here, causing a device-wide L2-invalidation storm)
//   - exit: ONE ACQUIRE load (single buffer_inv so subsequent normal loads
//     miss L1/L2 and fetch other blocks' data from LLC)
// Monotonic counters; leaf g at bar[g*32] (128 B apart), root bar[512], gen bar[576].
__device__ __forceinline__ void gbar(int* bar, int ibar) {
    __syncthreads();   // drains vmcnt for all waves of the block before arrival
    if (threadIdx.x == 0) {
        int g = blockIdx.x >> 5;
        int a = __hip_atomic_fetch_add(&bar[g * 32], 1, __ATOMIC_RELEASE,
                                       __HIP_MEMORY_SCOPE_AGENT);
        if (a == ibar * 32 + 31) {
            int r = __hip_atomic_fetch_add(&bar[512], 1, __ATOMIC_RELEASE,
                                           __HIP_MEMORY_SCOPE_AGENT);
            if (r == ibar * 8 + 7)
                __hip_atomic_store(&bar[576], ibar + 1, __ATOMIC_RELEASE,
                                   __HIP_MEMORY_SCOPE_AGENT);
        }
        while (__hip_atomic_load(&bar[576], __ATOMIC_RELAXED,
                                 __HIP_MEMORY_SCOPE_AGENT) <= ibar)
            __builtin_amdgcn_s_sleep(16);
        (void)__hip_atomic_load(&bar[576], __ATOMIC_ACQUIRE,
                                __HIP_MEMORY_SCOPE_AGENT);
    }
    __syncthreads();
}

// S0: zero state, barrier counters, and precompute token sequence.
__global__ void k_setup(const int* __restrict__ tgt, float* hx, float* cx,
                        float* obuf0, int* tok, int* bar) {
    int idx = blockIdx.x * 256 + threadIdx.x;
    if (idx < BD) { hx[idx] = 0.f; cx[idx] = 0.f; obuf0[idx] = 0.f; }
    if (blockIdx.x == 0) {
        for (int i = 0; i < 4; ++i) bar[threadIdx.x + i * 256] = 0;
        __shared__ int is64;
        if (threadIdx.x == 0) {
            int a = 1;
            for (int k = 0; k < 32; ++k) if (tgt[2 * k + 1] != 0) a = 0;
            is64 = a;
        }
        __syncthreads();
        int b = threadIdx.x;
        if (b < Bb) {
            int fin = 0;
            tok[0 * Bb + b] = 0;
            for (int s = 1; s < Ss; ++s) {
                int li = b * Tt + s;
                int nt = is64 ? tgt[2 * li] : tgt[li];
                if (nt == EOS_TOK) fin = 1;
                tok[s * Bb + b] = fin ? 0 : nt;
            }
        }
    }
}

// S1: Wv[b,n,d] = sum_c enc[b,n,c] * W_v[c,d]
__global__ void k_wv(const float* __restrict__ enc, const float* __restrict__ Wv_w,
                     float* __restrict__ Wv) {
    int b = blockIdx.x / 24, nt = blockIdx.x % 24, n0 = nt * 16;
    __shared__ float encL[16 * 512];
    for (int i = 0; i < 32; ++i) {
        int e = threadIdx.x + i * 256;
        int ni = e >> 9, c = e & 511;
        encL[e] = enc[((b * Nn) + (n0 + ni)) * Cc + c];
    }
    __syncthreads();
    int d0 = threadIdx.x, d1 = threadIdx.x + 256;
    float a0[16], a1[16];
#pragma unroll
    for (int i = 0; i < 16; ++i) { a0[i] = 0.f; a1[i] = 0.f; }
    for (int c = 0; c < 512; ++c) {
        float w0 = Wv_w[c * Dd + d0], w1 = Wv_w[c * Dd + d1];
#pragma unroll
        for (int i = 0; i < 16; ++i) {
            float ev = encL[i * 512 + c];
            a0[i] += ev * w0; a1[i] += ev * w1;
        }
    }
#pragma unroll
    for (int i = 0; i < 16; ++i) {
        Wv[((b * Nn) + (n0 + i)) * Dd + d0] = a0[i];
        Wv[((b * Nn) + (n0 + i)) * Dd + d1] = a1[i];
    }
}

// Persistent decode loop: 191 steps, 8 phases/step, device barriers between.
__global__ __launch_bounds__(256, 1) void k_decode(
    const float* __restrict__ enc, const float* __restrict__ emb,
    const float* __restrict__ W_ih, const float* __restrict__ b_ih,
    const float* __restrict__ W_hh, const float* __restrict__ b_hh,
    const float* __restrict__ W_h, const float* __restrict__ vv,
    const float* __restrict__ W_c, const float* __restrict__ b_c,
    const int* __restrict__ tok, const float* __restrict__ Wv,
    float* __restrict__ part, float* __restrict__ qpart, float* __restrict__ opart,
    float* __restrict__ hx, float* __restrict__ cx, float* __restrict__ q,
    float* __restrict__ ctx, float* __restrict__ sc, float* __restrict__ obuf,
    float* __restrict__ out_alphas, int* bar)
{
    __shared__ float smem[5120];
    const int bid = blockIdx.x, tid = threadIdx.x;
    const int lane = tid & 63;
    int ib = 0;

    for (int t = 0; t < Ss; ++t) {
        // ---------- Phase A: gates partials (jt = bid&31 over 64 j, ks = bid>>5) ----------
        {
            const float* o_prev = obuf + (size_t)t * BD;
            int jt = bid & 31, ks = bid >> 5;
            int j0 = jt * 64;
            for (int i = 0; i < 20; ++i) {
                int e = tid + i * 256;
                int b = e / KCH, k = e - b * KCH;
                int kg = ks * KCH + k;
                float val;
                if (kg < Ee)            val = emb[tok[t * Bb + b] * Ee + kg];
                else if (kg < Ee + Dd)  val = o_prev[b * Dd + (kg - Ee)];
                else                    val = hx[b * Dd + (kg - Ee - Dd)];
                smem[k * 32 + b] = val;
            }
            __syncthreads();
            int jl = tid & 63, bg = tid >> 6;
            int j = j0 + jl;
            float acc[8];
#pragma unroll
            for (int i = 0; i < 8; ++i) acc[i] = 0.f;
            for (int k = 0; k < KCH; ++k) {
                int kg = ks * KCH + k;
                const float* wrow = (kg < Ee + Dd) ? (W_ih + (size_t)kg * G4)
                                                   : (W_hh + (size_t)(kg - Ee - Dd) * G4);
                float w = wrow[j];
                float4 xa = *(const float4*)&smem[k * 32 + bg * 8];
                float4 xb = *(const float4*)&smem[k * 32 + bg * 8 + 4];
                acc[0] += xa.x * w; acc[1] += xa.y * w; acc[2] += xa.z * w; acc[3] += xa.w * w;
                acc[4] += xb.x * w; acc[5] += xb.y * w; acc[6] += xb.z * w; acc[7] += xb.w * w;
            }
#pragma unroll
            for (int i = 0; i < 8; ++i)
                part[ks * (Bb * G4) + (bg * 8 + i) * G4 + j] = acc[i];
        }
        gbar(bar, ib++);

        // ---------- Phase B: LSTM pointwise + zero ctx ----------
        if (tid < 64) {
            int idx = bid * 64 + tid;
            int b = idx >> 9, d = idx & 511;
            float g[4];
#pragma unroll
            for (int gi = 0; gi < 4; ++gi) {
                int j = gi * Dd + d;
                float s = b_ih[j] + b_hh[j];
#pragma unroll
                for (int ks = 0; ks < KSPLIT; ++ks)
                    s += part[ks * (Bb * G4) + b * G4 + j];
                g[gi] = s;
            }
            float i_ = sigm_(g[0]), f_ = sigm_(g[1]), gg = tanh_(g[2]), oo = sigm_(g[3]);
            float c = f_ * cx[idx] + i_ * gg;
            cx[idx] = c;
            hx[idx] = oo * tanh_(c);
            ctx[idx] = 0.f;
        }
        gbar(bar, ib++);

        // ---------- Phase C1: q partials (dt 16 x kt 16, all 32 b per block) ----------
        {
            float* WL  = smem;          // 32 x (32 pad 36)
            float* hxL = smem + 1152;   // 32 x (32 pad 36)
            int kt = bid & 15, dt = bid >> 4;
            int k0 = kt * 32, d0 = dt * 32;
            {
                int r = tid >> 3, c4 = (tid & 7) * 4;
                *(float4*)&WL[r * 36 + c4]  = *(const float4*)&W_h[(size_t)(k0 + r) * Dd + d0 + c4];
                *(float4*)&hxL[r * 36 + c4] = *(const float4*)&hx[r * Dd + k0 + c4];
            }
            __syncthreads();
            int bb = tid >> 3, dl4 = (tid & 7) * 4;
            float4 acc = {0.f, 0.f, 0.f, 0.f};
            for (int k = 0; k < 32; ++k) {
                float h = hxL[bb * 36 + k];
                float4 w = *(const float4*)&WL[k * 36 + dl4];
                acc.x += h * w.x; acc.y += h * w.y; acc.z += h * w.z; acc.w += h * w.w;
            }
            *(float4*)&qpart[kt * 16384 + bb * 512 + d0 + dl4] = acc;
        }
        gbar(bar, ib++);

        // ---------- Phase C2: q reduce ----------
        if (tid < 64) {
            int idx = bid * 64 + tid;
            float s = 0.f;
#pragma unroll
            for (int kt = 0; kt < 16; ++kt) s += qpart[kt * 16384 + idx];
            q[idx] = s;
        }
        gbar(bar, ib++);

        // ---------- Phase D: scores (1024 waves x 12 (b,n) pairs) ----------
        {
            int w = bid * 4 + (tid >> 6);
            float4 v0 = *(const float4*)&vv[lane * 4];
            float4 v1 = *(const float4*)&vv[256 + lane * 4];
#pragma unroll
            for (int r = 0; r < 12; ++r) {
                int p = w * 12 + r;
                int b = p / 384;
                const float* wvp = Wv + (size_t)p * Dd;
                const float* qb = q + b * Dd;
                float4 wa = *(const float4*)&wvp[lane * 4];
                float4 wb = *(const float4*)&wvp[256 + lane * 4];
                float4 qa = *(const float4*)&qb[lane * 4];
                float4 qc = *(const float4*)&qb[256 + lane * 4];
                float a = v0.x * tanh_(qa.x + wa.x) + v0.y * tanh_(qa.y + wa.y)
                        + v0.z * tanh_(qa.z + wa.z) + v0.w * tanh_(qa.w + wa.w)
                        + v1.x * tanh_(qc.x + wb.x) + v1.y * tanh_(qc.y + wb.y)
                        + v1.z * tanh_(qc.z + wb.z) + v1.w * tanh_(qc.w + wb.w);
#pragma unroll
                for (int off = 32; off > 0; off >>= 1)
                    a += __shfl_down(a, off, 64);
                if (lane == 0) sc[p] = a;
            }
        }
        gbar(bar, ib++);

        // ---------- Phase E: softmax + alpha out + ctx atomics ----------
        {
            float* eL  = smem;          // 384
            float* red = smem + 384;    // 256
            float* aL  = smem + 640;    // 48
            int b = bid >> 3, sl = bid & 7;
            float m = -1e30f;
            for (int n = tid; n < Nn; n += 256) m = fmaxf(m, sc[b * Nn + n]);
            red[tid] = m; __syncthreads();
            for (int s = 128; s > 0; s >>= 1) {
                if (tid < s) red[tid] = fmaxf(red[tid], red[tid + s]);
                __syncthreads();
            }
            m = red[0]; __syncthreads();
            float ps = 0.f;
            for (int n = tid; n < Nn; n += 256) {
                float e = __expf(sc[b * Nn + n] - m);
                eL[n] = e; ps += e;
            }
            red[tid] = ps; __syncthreads();
            for (int s = 128; s > 0; s >>= 1) {
                if (tid < s) red[tid] += red[tid + s];
                __syncthreads();
            }
            float inv = 1.0f / red[0];
            int n0 = sl * 48;
            if (tid < 48) {
                float a = eL[n0 + tid] * inv;
                aL[tid] = a;
                out_alphas[b * (Ss * Nn) + t * Nn + n0 + tid] = a;
            }
            __syncthreads();
            int c0 = tid, c1 = tid + 256;
            float acc0 = 0.f, acc1 = 0.f;
            for (int i = 0; i < 48; ++i) {
                float a = aL[i];
                const float* er = enc + (size_t)((b * Nn) + (n0 + i)) * Cc;
                acc0 += a * er[c0];
                acc1 += a * er[c1];
            }
            atomicAdd(&ctx[b * Cc + c0], acc0);
            atomicAdd(&ctx[b * Cc + c1], acc1);
        }
        gbar(bar, ib++);

        // ---------- Phase F1: o_t partials (dt 16 x kt 16 over 1024 k, all b) ----------
        {
            float* WL = smem;           // 64 x (32 pad 36) = 2304
            float* xL = smem + 2304;    // 32 x (64 pad 68) = 2176
            int kt = bid & 15, dt = bid >> 4;
            int k0 = kt * 64, d0 = dt * 32;
            for (int e = tid; e < 512; e += 256) {
                int r = e >> 3, c4 = (e & 7) * 4;
                *(float4*)&WL[r * 36 + c4] = *(const float4*)&W_c[(size_t)(k0 + r) * Dd + d0 + c4];
            }
            const float* xsrc = (k0 < 512) ? (hx + k0) : (ctx + (k0 - 512));
            for (int e = tid; e < 512; e += 256) {
                int b = e >> 4, k4 = (e & 15) * 4;
                *(float4*)&xL[b * 68 + k4] = *(const float4*)&xsrc[b * 512 + k4];
            }
            __syncthreads();
            int bb = tid >> 3, dl4 = (tid & 7) * 4;
            float4 acc = {0.f, 0.f, 0.f, 0.f};
            for (int k = 0; k < 64; ++k) {
                float x = xL[bb * 68 + k];
                float4 w = *(const float4*)&WL[k * 36 + dl4];
                acc.x += x * w.x; acc.y += x * w.y; acc.z += x * w.z; acc.w += x * w.w;
            }
            *(float4*)&opart[kt * 16384 + bb * 512 + d0 + dl4] = acc;
        }
        gbar(bar, ib++);

        // ---------- Phase F2: o reduce + tanh -> obuf[t+1] ----------
        if (tid < 64) {
            int idx = bid * 64 + tid;
            int d = idx & 511;
            float s = b_c[d];
#pragma unroll
            for (int kt = 0; kt < 16; ++kt) s += opart[kt * 16384 + idx];
            obuf[(size_t)(t + 1) * BD + idx] = tanh_(s);
        }
        gbar(bar, ib++);
    }
}

// Deferred logits GEMM.
__global__ void k_logits(const float* __restrict__ obuf, const float* __restrict__ W_out,
                         const float* __restrict__ b_out, float* __restrict__ out_logits) {
    int b = blockIdx.x / 24, tt = blockIdx.x % 24;
    int t0 = tt * 8;
    int tmax = min(8, Ss - t0);
    __shared__ float oL[8 * 512];
    int tid = threadIdx.x;
    for (int i = 0; i < 16; ++i) {
        int e = tid + i * 256;
        int ti = e >> 9, d = e & 511;
        oL[e] = (ti < tmax) ? obuf[(size_t)(t0 + ti + 1) * BD + b * Dd + d] : 0.f;
    }
    __syncthreads();
    int v0 = tid, v1 = tid + 256, v2 = tid + 512;
    bool h2 = (v2 < Vv);
    int v2c = h2 ? v2 : 0;
    float acc[3][8];
#pragma unroll
    for (int s = 0; s < 3; ++s)
#pragma unroll
        for (int ti = 0; ti < 8; ++ti) acc[s][ti] = 0.f;
    for (int d = 0; d < 512; ++d) {
        float w0 = W_out[d * Vv + v0];
        float w1 = W_out[d * Vv + v1];
        float w2 = W_out[d * Vv + v2c];
#pragma unroll
        for (int ti = 0; ti < 8; ++ti) {
            float o = oL[ti * 512 + d];
            acc[0][ti] += o * w0; acc[1][ti] += o * w1; acc[2][ti] += o * w2;
        }
    }
    for (int ti = 0; ti < tmax; ++ti) {
        size_t base = (size_t)b * (Ss * Vv) + (size_t)(t0 + ti) * Vv;
        out_logits[base + v0] = acc[0][ti] + b_out[v0];
        out_logits[base + v1] = acc[1][ti] + b_out[v1];
        if (h2) out_logits[base + v2] = acc[2][ti] + b_out[v2];
    }
}

extern "C" void kernel_launch(void* const* d_in, const int* in_sizes, int n_in,
                              void* d_out, int out_size, void* d_ws, size_t ws_size,
                              hipStream_t stream) {
    const float* enc   = (const float*)d_in[0];
    const int*   tgt   = (const int*)d_in[1];
    const float* emb   = (const float*)d_in[2];
    const float* W_ih  = (const float*)d_in[3];
    const float* b_ih  = (const float*)d_in[4];
    const float* W_hh  = (const float*)d_in[5];
    const float* b_hh  = (const float*)d_in[6];
    const float* W_h   = (const float*)d_in[7];
    const float* W_v   = (const float*)d_in[8];
    const float* vv    = (const float*)d_in[9];
    const float* W_c   = (const float*)d_in[10];
    const float* b_c   = (const float*)d_in[11];
    const float* W_out = (const float*)d_in[12];
    const float* b_out = (const float*)d_in[13];

    float* wsf   = (float*)d_ws;
    int*   tok   = (int*)d_ws;
    float* part  = wsf + OFF_PART;
    float* qpart = wsf + OFF_QPART;
    float* opart = wsf + OFF_OPART;
    float* Wv    = wsf + OFF_WV;
    float* hx    = wsf + OFF_HX;
    float* cx    = wsf + OFF_CX;
    float* q     = wsf + OFF_Q;
    float* ctx   = wsf + OFF_CTX;
    float* sc    = wsf + OFF_SC;
    float* obuf  = wsf + OFF_OBUF;
    int*   bar   = (int*)(wsf + OFF_BAR);

    float* out_logits = (float*)d_out;
    float* out_alphas = (float*)d_out + LOGITS_SZ;

    k_setup<<<64, 256, 0, stream>>>(tgt, hx, cx, obuf, tok, bar);
    k_wv<<<768, 256, 0, stream>>>(enc, W_v, Wv);
    k_decode<<<NB, 256, 0, stream>>>(enc, emb, W_ih, b_ih, W_hh, b_hh, W_h, vv,
                                     W_c, b_c, tok, Wv, part, qpart, opart,
                                     hx, cx, q, ctx, sc, obuf, out_alphas, bar);
    k_logits<<<768, 256, 0, stream>>>(obuf, W_out, b_out, out_logits);
}

// Round 5
// 18201.535 us; speedup vs baseline: 5.2531x; 1.4193x over previous
//
#include <hip/hip_runtime.h>
#include <cstdint>

#define Bb 32
#define Cc 512
#define Nn 384
#define Vv 600
#define Ee 256
#define Dd 512
#define Tt 192
#define Ss 191
#define EOS_TOK 130
#define BD (Bb*Dd)          // 16384
#define NBLK 256
#define NTHR 512

// ---- ws layout (float offsets) ----
#define OFF_TOK   0                      // int tok[Ss*Bb]
#define OFF_SHIFT 8192                   // float shift[1]
#define OFF_WV    8256                   // Bb*Nn*Dd = 6291456
#define OFF_HXT   (OFF_WV + 6291456)     // 2 * 512*32 (double-buffered, [d][b])
#define OFF_XO    (OFF_HXT + 32768)      // 512*32 o_prev transposed [d][b]
#define OFF_CX    (OFF_XO + 16384)       // [d][b]
#define OFF_DEN   (OFF_CX + 16384)       // denom[t][b] 191*32 (pad 8192)
#define OFF_Q     (OFF_DEN + 8192)       // q[b][d] 32*512
#define OFF_CTX   (OFF_Q + 16384)        // ctxT[c][b] 512*32
#define OFF_OBUF  (OFF_CTX + 16384)      // 192*BD; slot t+1 front 8192 doubles as embx[t]
#define OFF_BAR   (OFF_OBUF + 192*16384) // 1024 ints

#define LOGITS_SZ (Bb*Ss*Vv)  // 3667200
#define ALPHA_SZ  (Bb*Ss*Nn)  // 2347008

__device__ __forceinline__ float sigm_(float x) {
    float e = __expf(-x);
    return __builtin_amdgcn_rcpf(1.0f + e);
}
__device__ __forceinline__ float tanh_(float x) {
    float xc = fminf(15.0f, fmaxf(-15.0f, x));
    float e = __expf(2.0f * xc);
    return (e - 1.0f) * __builtin_amdgcn_rcpf(e + 1.0f);
}

// Device barrier: 16 leaves x 16 blocks + root + gen flag. RELEASE arrival
// (one wbl2/block), RELAXED spin (no inv per poll), single ACQUIRE at exit
// (one L1+L2 inv per block; LDS-resident weights are immune to the inv).
__device__ __forceinline__ void gbar(int* bar, int ibar) {
    __syncthreads();
    if (threadIdx.x == 0) {
        int g = blockIdx.x >> 4;
        int a = __hip_atomic_fetch_add(&bar[g * 32], 1, __ATOMIC_RELEASE,
                                       __HIP_MEMORY_SCOPE_AGENT);
        if (a == ibar * 16 + 15) {
            int r = __hip_atomic_fetch_add(&bar[640], 1, __ATOMIC_RELEASE,
                                           __HIP_MEMORY_SCOPE_AGENT);
            if (r == ibar * 16 + 15)
                __hip_atomic_store(&bar[704], ibar + 1, __ATOMIC_RELEASE,
                                   __HIP_MEMORY_SCOPE_AGENT);
        }
        while (__hip_atomic_load(&bar[704], __ATOMIC_RELAXED,
                                 __HIP_MEMORY_SCOPE_AGENT) <= ibar)
            __builtin_amdgcn_s_sleep(4);
        (void)__hip_atomic_load(&bar[704], __ATOMIC_ACQUIRE,
                                __HIP_MEMORY_SCOPE_AGENT);
    }
    __syncthreads();
}

// S0: zero state/barriers/denoms, token sequence, exp-shift = sum|v|.
__global__ void k_setup(const int* __restrict__ tgt, const float* __restrict__ vv,
                        float* zbase, int* bar, int* tok, float* shiftbuf) {
    int gid = blockIdx.x * 256 + threadIdx.x;
    // zero hxT(32768)+xo(16384)+cx(16384)+den(8192) = 73728 floats
    for (int i = gid; i < 73728; i += 96 * 256) zbase[i] = 0.f;
    if (gid < 1024) bar[gid] = 0;
    if (blockIdx.x == 0) {
        __shared__ int is64;
        if (threadIdx.x == 0) {
            int a = 1;
            for (int k = 0; k < 32; ++k) if (tgt[2 * k + 1] != 0) a = 0;
            is64 = a;
        }
        __syncthreads();
        int b = threadIdx.x;
        if (b < Bb) {
            int fin = 0;
            tok[0 * Bb + b] = 0;
            for (int s = 1; s < Ss; ++s) {
                int li = b * Tt + s;
                int nt = is64 ? tgt[2 * li] : tgt[li];
                if (nt == EOS_TOK) fin = 1;
                tok[s * Bb + b] = fin ? 0 : nt;
            }
        }
    }
    if (blockIdx.x == 1) {
        __shared__ float sred[256];
        int tid = threadIdx.x;
        sred[tid] = fabsf(vv[tid]) + fabsf(vv[tid + 256]);
        __syncthreads();
        for (int s = 128; s > 0; s >>= 1) {
            if (tid < s) sred[tid] += sred[tid + s];
            __syncthreads();
        }
        if (tid == 0) shiftbuf[0] = sred[0];
    }
}

// S1: gather embeddings for all steps into obuf slot fronts: [t][k][b]
__global__ void k_embx(const float* __restrict__ emb, const int* __restrict__ tok,
                       float* __restrict__ obuf) {
    int i = blockIdx.x * 256 + threadIdx.x;   // over 191*8192
    if (i < Ss * 8192) {
        int t = i >> 13, e = i & 8191;
        int k = e >> 5, b = e & 31;
        obuf[(size_t)(t + 1) * BD + e] = emb[(size_t)tok[t * 32 + b] * Ee + k];
    }
}

// S2: Wv[b,n,d] = sum_c enc[b,n,c] * W_v[c,d]
__global__ void k_wv(const float* __restrict__ enc, const float* __restrict__ Wv_w,
                     float* __restrict__ Wv) {
    int b = blockIdx.x / 24, nt = blockIdx.x % 24, n0 = nt * 16;
    __shared__ float encL[16 * 512];
    for (int i = 0; i < 32; ++i) {
        int e = threadIdx.x + i * 256;
        int ni = e >> 9, c = e & 511;
        encL[e] = enc[((b * Nn) + (n0 + ni)) * Cc + c];
    }
    __syncthreads();
    int d0 = threadIdx.x, d1 = threadIdx.x + 256;
    float a0[16], a1[16];
#pragma unroll
    for (int i = 0; i < 16; ++i) { a0[i] = 0.f; a1[i] = 0.f; }
    for (int c = 0; c < 512; ++c) {
        float w0 = Wv_w[c * Dd + d0], w1 = Wv_w[c * Dd + d1];
#pragma unroll
        for (int i = 0; i < 16; ++i) {
            float ev = encL[i * 512 + c];
            a0[i] += ev * w0; a1[i] += ev * w1;
        }
    }
#pragma unroll
    for (int i = 0; i < 16; ++i) {
        Wv[((b * Nn) + (n0 + i)) * Dd + d0] = a0[i];
        Wv[((b * Nn) + (n0 + i)) * Dd + d1] = a1[i];
    }
}

// Persistent decode: 256 blocks x 512 threads, weights LDS-resident,
// 4 device barriers per step. Block bid owns output dims {2*bid, 2*bid+1}.
__global__ __launch_bounds__(NTHR) void k_decode(
    const float* __restrict__ enc, const float* __restrict__ W_ih,
    const float* __restrict__ b_ih, const float* __restrict__ W_hh,
    const float* __restrict__ b_hh, const float* __restrict__ W_h,
    const float* __restrict__ vv, const float* __restrict__ W_c,
    const float* __restrict__ b_c, const float* __restrict__ Wv,
    const float* __restrict__ shiftbuf,
    float* __restrict__ hxT, float* __restrict__ xo, float* __restrict__ cx,
    float* __restrict__ den, float* __restrict__ q, float* __restrict__ ctxT,
    float* __restrict__ obuf, float* __restrict__ alpha_e, int* bar)
{
    __shared__ float Wg[1280 * 8];    // gates cols: [k][g*2+dd]   40960B
    __shared__ float Whx[512 * 2];    // W_h cols    [d][dd]        4096B
    __shared__ float Wc[1024 * 2];    // W_c cols    [k][dd]        8192B
    __shared__ float scratch[2048];   // phase-local                8192B

    const int tid = threadIdx.x, bid = blockIdx.x;
    const int lane = tid & 63;
    const int d0 = bid * 2;

    // ---- one-time weight staging into LDS ----
    for (int k = tid; k < 1280; k += NTHR) {
        const float* src = (k < 768) ? (W_ih + (size_t)k * 2048)
                                     : (W_hh + (size_t)(k - 768) * 2048);
#pragma unroll
        for (int g = 0; g < 4; ++g) {
            Wg[k * 8 + g * 2 + 0] = src[g * 512 + d0 + 0];
            Wg[k * 8 + g * 2 + 1] = src[g * 512 + d0 + 1];
        }
    }
    {
        int d = tid;  // NTHR == 512
        Whx[d * 2 + 0] = W_h[(size_t)d * 512 + d0 + 0];
        Whx[d * 2 + 1] = W_h[(size_t)d * 512 + d0 + 1];
    }
    for (int k = tid; k < 1024; k += NTHR) {
        Wc[k * 2 + 0] = W_c[(size_t)k * 512 + d0 + 0];
        Wc[k * 2 + 1] = W_c[(size_t)k * 512 + d0 + 1];
    }
    float v8[8];
#pragma unroll
    for (int i = 0; i < 8; ++i) v8[i] = vv[lane + i * 64];
    const float SHIFT = shiftbuf[0];
    float bsum0 = 0.f, bsum1 = 0.f, bsum2 = 0.f, bsum3 = 0.f, bcv = 0.f;
    if (tid < 64) {
        int dd = tid >> 5;
        int d = d0 + dd;
        bsum0 = b_ih[0 * 512 + d] + b_hh[0 * 512 + d];
        bsum1 = b_ih[1 * 512 + d] + b_hh[1 * 512 + d];
        bsum2 = b_ih[2 * 512 + d] + b_hh[2 * 512 + d];
        bsum3 = b_ih[3 * 512 + d] + b_hh[3 * 512 + d];
        bcv = b_c[d];
    }
    __syncthreads();

    int ib = 0;
    for (int t = 0; t < Ss; ++t) {
        const int rd = t & 1, wr = 1 - rd;
        float* hxT_rd = hxT + rd * 16384;
        float* hxT_wr = hxT + wr * 16384;

        // ---------- Phase A: gates (full K) + LSTM ----------
        {
            const float* embx_t = obuf + (size_t)(t + 1) * BD;  // [k][b], k<256
            const float* xo2 = xo - 256 * 32;
            const float* hx2 = hxT_rd - 768 * 32;
            int b = tid & 31, cq = (tid >> 5) & 1, ks = tid >> 6;
            int k0 = ks * 160;
            float a0 = 0.f, a1 = 0.f, a2 = 0.f, a3 = 0.f;
#pragma unroll 8
            for (int k = k0; k < k0 + 160; ++k) {
                const float* base = (k < 256) ? embx_t : ((k < 768) ? xo2 : hx2);
                float x = base[k * 32 + b];
                float4 w = *(const float4*)&Wg[k * 8 + cq * 4];
                a0 += x * w.x; a1 += x * w.y; a2 += x * w.z; a3 += x * w.w;
            }
            int c0 = cq * 4;
            scratch[((ks * 8) + c0 + 0) * 32 + b] = a0;
            scratch[((ks * 8) + c0 + 1) * 32 + b] = a1;
            scratch[((ks * 8) + c0 + 2) * 32 + b] = a2;
            scratch[((ks * 8) + c0 + 3) * 32 + b] = a3;
            __syncthreads();
            if (tid < 256) {
                int col = tid >> 5, b2 = tid & 31;
                float s = 0.f;
#pragma unroll
                for (int k2 = 0; k2 < 8; ++k2) s += scratch[(k2 * 8 + col) * 32 + b2];
                scratch[col * 32 + b2] = s;   // safe: slot read only by this thread
            }
            __syncthreads();
            if (tid < 64) {
                int dd = tid >> 5, b2 = tid & 31;
                float gi = scratch[(0 * 2 + dd) * 32 + b2] + bsum0;
                float gf = scratch[(1 * 2 + dd) * 32 + b2] + bsum1;
                float gg = scratch[(2 * 2 + dd) * 32 + b2] + bsum2;
                float go = scratch[(3 * 2 + dd) * 32 + b2] + bsum3;
                int ci = (d0 + dd) * 32 + b2;
                float c = sigm_(gf) * cx[ci] + sigm_(gi) * tanh_(gg);
                cx[ci] = c;
                hxT_wr[ci] = sigm_(go) * tanh_(c);
            }
        }
        gbar(bar, ib++);

        // ---------- Phase C: q = hx @ W_h (2 cols) + zero ctxT slice ----------
        {
            if (tid < 64)
                __hip_atomic_store(&ctxT[bid * 64 + tid], 0.f, __ATOMIC_RELAXED,
                                   __HIP_MEMORY_SCOPE_AGENT);
            int b = tid & 31, jj = (tid >> 5) & 1, dc = tid >> 6;
            float a = 0.f;
#pragma unroll 8
            for (int d = dc * 64; d < dc * 64 + 64; ++d)
                a += hxT_wr[d * 32 + b] * Whx[d * 2 + jj];
            scratch[(dc * 2 + jj) * 32 + b] = a;
            __syncthreads();
            if (tid < 64) {
                int jj2 = tid >> 5, b2 = tid & 31;
                float s = 0.f;
#pragma unroll
                for (int d2 = 0; d2 < 8; ++d2) s += scratch[(d2 * 2 + jj2) * 32 + b2];
                q[b2 * 512 + d0 + jj2] = s;
            }
        }
        gbar(bar, ib++);

        // ---------- Phase DE: scores + exp(shifted) + ctx atomics ----------
        {
            float* esc = scratch;            // 48 e-values
            int b = bid >> 3, n0 = (bid & 7) * 48;
            int w = tid >> 6;
            float q8[8];
#pragma unroll
            for (int i = 0; i < 8; ++i) q8[i] = q[b * 512 + lane + i * 64];
#pragma unroll
            for (int r = 0; r < 6; ++r) {
                int n = n0 + w * 6 + r;
                const float* wv = Wv + ((size_t)(b * Nn + n)) * 512;
                float s = 0.f;
#pragma unroll
                for (int i = 0; i < 8; ++i)
                    s += v8[i] * tanh_(q8[i] + wv[lane + i * 64]);
#pragma unroll
                for (int off = 32; off > 0; off >>= 1)
                    s += __shfl_down(s, off, 64);
                if (lane == 0) esc[w * 6 + r] = __expf(s - SHIFT);
            }
            __syncthreads();
            if (tid < 48)
                alpha_e[((size_t)b * Ss + t) * Nn + n0 + tid] = esc[tid];
            if (tid == 0) {
                float sd = 0.f;
                for (int i = 0; i < 48; ++i) sd += esc[i];
                atomicAdd(&den[t * 32 + b], sd);
            }
            int c = tid;
            float acc = 0.f;
#pragma unroll 8
            for (int i = 0; i < 48; ++i)
                acc += esc[i] * enc[((size_t)(b * Nn + n0 + i)) * 512 + c];
            atomicAdd(&ctxT[c * 32 + b], acc);
        }
        gbar(bar, ib++);

        // ---------- Phase F: o_t = tanh([hx|ctx/den] @ W_c + b_c) (2 cols) ----------
        {
            int b = tid & 31, dd = (tid >> 5) & 1, kc = tid >> 6;
            const float* base = (kc < 4) ? hxT_wr : (ctxT - 512 * 32);
            // ctx half must be normalized by the softmax denominator (exact IEEE div;
            // den complete after the DE->F barrier). Round-4 bug: this was missing.
            float dinv = (kc >= 4) ? (1.0f / den[t * 32 + b]) : 1.0f;
            float a = 0.f;
#pragma unroll 8
            for (int k = kc * 128; k < kc * 128 + 128; ++k)
                a += base[k * 32 + b] * Wc[k * 2 + dd];
            a *= dinv;
            scratch[(kc * 2 + dd) * 32 + b] = a;
            __syncthreads();
            if (tid < 64) {
                int dd2 = tid >> 5, b2 = tid & 31;
                float s = bcv;
#pragma unroll
                for (int k2 = 0; k2 < 8; ++k2) s += scratch[(k2 * 2 + dd2) * 32 + b2];
                float o = tanh_(s);
                xo[(d0 + dd2) * 32 + b2] = o;
                obuf[(size_t)(t + 1) * BD + b2 * 512 + d0 + dd2] = o;
            }
        }
        gbar(bar, ib++);
    }
}

// Deferred logits GEMM.
__global__ void k_logits(const float* __restrict__ obuf, const float* __restrict__ W_out,
                         const float* __restrict__ b_out, float* __restrict__ out_logits) {
    int b = blockIdx.x / 24, tt = blockIdx.x % 24;
    int t0 = tt * 8;
    int tmax = min(8, Ss - t0);
    __shared__ float oL[8 * 512];
    int tid = threadIdx.x;
    for (int i = 0; i < 16; ++i) {
        int e = tid + i * 256;
        int ti = e >> 9, d = e & 511;
        oL[e] = (ti < tmax) ? obuf[(size_t)(t0 + ti + 1) * BD + b * Dd + d] : 0.f;
    }
    __syncthreads();
    int v0 = tid, v1 = tid + 256, v2 = tid + 512;
    bool h2 = (v2 < Vv);
    int v2c = h2 ? v2 : 0;
    float acc[3][8];
#pragma unroll
    for (int s = 0; s < 3; ++s)
#pragma unroll
        for (int ti = 0; ti < 8; ++ti) acc[s][ti] = 0.f;
    for (int d = 0; d < 512; ++d) {
        float w0 = W_out[d * Vv + v0];
        float w1 = W_out[d * Vv + v1];
        float w2 = W_out[d * Vv + v2c];
#pragma unroll
        for (int ti = 0; ti < 8; ++ti) {
            float o = oL[ti * 512 + d];
            acc[0][ti] += o * w0; acc[1][ti] += o * w1; acc[2][ti] += o * w2;
        }
    }
    for (int ti = 0; ti < tmax; ++ti) {
        size_t base = (size_t)b * (Ss * Vv) + (size_t)(t0 + ti) * Vv;
        out_logits[base + v0] = acc[0][ti] + b_out[v0];
        out_logits[base + v1] = acc[1][ti] + b_out[v1];
        if (h2) out_logits[base + v2] = acc[2][ti] + b_out[v2];
    }
}

// Normalize alphas: alpha /= denom[b,t]
__global__ void k_anorm(float* __restrict__ alph, const float* __restrict__ den) {
    int i = blockIdx.x * 256 + threadIdx.x;
    if (i < ALPHA_SZ) {
        int bt = i / Nn;
        int t = bt % Ss, b = bt / Ss;
        alph[i] = alph[i] / den[t * 32 + b];
    }
}

extern "C" void kernel_launch(void* const* d_in, const int* in_sizes, int n_in,
                              void* d_out, int out_size, void* d_ws, size_t ws_size,
                              hipStream_t stream) {
    const float* enc   = (const float*)d_in[0];
    const int*   tgt   = (const int*)d_in[1];
    const float* emb   = (const float*)d_in[2];
    const float* W_ih  = (const float*)d_in[3];
    const float* b_ih  = (const float*)d_in[4];
    const float* W_hh  = (const float*)d_in[5];
    const float* b_hh  = (const float*)d_in[6];
    const float* W_h   = (const float*)d_in[7];
    const float* W_v   = (const float*)d_in[8];
    const float* vv    = (const float*)d_in[9];
    const float* W_c   = (const float*)d_in[10];
    const float* b_c   = (const float*)d_in[11];
    const float* W_out = (const float*)d_in[12];
    const float* b_out = (const float*)d_in[13];

    float* wsf   = (float*)d_ws;
    int*   tok   = (int*)d_ws;
    float* shiftb= wsf + OFF_SHIFT;
    float* Wv    = wsf + OFF_WV;
    float* hxT   = wsf + OFF_HXT;
    float* xo    = wsf + OFF_XO;
    float* cx    = wsf + OFF_CX;
    float* den   = wsf + OFF_DEN;
    float* q     = wsf + OFF_Q;
    float* ctxT  = wsf + OFF_CTX;
    float* obuf  = wsf + OFF_OBUF;
    int*   bar   = (int*)(wsf + OFF_BAR);

    float* out_logits = (float*)d_out;
    float* out_alphas = (float*)d_out + LOGITS_SZ;

    k_setup<<<96, 256, 0, stream>>>(tgt, vv, hxT, bar, tok, shiftb);
    k_embx<<<(Ss * 8192 + 255) / 256, 256, 0, stream>>>(emb, tok, obuf);
    k_wv<<<768, 256, 0, stream>>>(enc, W_v, Wv);
    k_decode<<<NBLK, NTHR, 0, stream>>>(enc, W_ih, b_ih, W_hh, b_hh, W_h, vv,
                                        W_c, b_c, Wv, shiftb,
                                        hxT, xo, cx, den, q, ctxT, obuf,
                                        out_alphas, bar);
    k_logits<<<768, 256, 0, stream>>>(obuf, W_out, b_out, out_logits);
    k_anorm<<<(ALPHA_SZ + 255) / 256, 256, 0, stream>>>(out_alphas, den);
}

// Round 6
// 8431.158 us; speedup vs baseline: 11.3405x; 2.1588x over previous
//
#include <hip/hip_runtime.h>
#include <cstdint>

#define Bb 32
#define Cc 512
#define Nn 384
#define Vv 600
#define Ee 256
#define Dd 512
#define Tt 192
#define Ss 191
#define EOS_TOK 130
#define BD (Bb*Dd)          // 16384
#define NBLK 256
#define NTHR 512

// ---- ws layout (float offsets) ----
#define OFF_TOK   0                      // int tok[Ss*Bb]
#define OFF_SHIFT 8192                   // float shift[1]
#define OFF_WV    8256                   // Bb*Nn*Dd = 6291456
#define OFF_HXT   (OFF_WV + 6291456)     // 2 * 512*32 (double-buffered, [d][b])
#define OFF_XO    (OFF_HXT + 32768)      // 512*32 o_prev transposed [d][b]
#define OFF_CX    (OFF_XO + 16384)       // [d][b]
#define OFF_DEN   (OFF_CX + 16384)       // denom[t][b] 191*32 (pad 8192)
#define OFF_Q     (OFF_DEN + 8192)       // q[b][d] 32*512
#define OFF_CTX   (OFF_Q + 16384)        // ctxT[c][b] 512*32
#define OFF_OBUF  (OFF_CTX + 16384)      // 192*BD; slot t+1 front 8192 doubles as embx[t]
#define OFF_BAR   (OFF_OBUF + 192*16384) // 1024 ints

#define LOGITS_SZ (Bb*Ss*Vv)  // 3667200
#define ALPHA_SZ  (Bb*Ss*Nn)  // 2347008

__device__ __forceinline__ float sigm_(float x) {
    float e = __expf(-x);
    return __builtin_amdgcn_rcpf(1.0f + e);
}
__device__ __forceinline__ float tanh_(float x) {
    float xc = fminf(15.0f, fmaxf(-15.0f, x));
    float e = __expf(2.0f * xc);
    return (e - 1.0f) * __builtin_amdgcn_rcpf(e + 1.0f);
}

// Device-coherent (LLC) scalar access: agent-scope relaxed atomics compile to
// sc1 bypass/write-through ops — coherent across XCDs with NO cache-wide
// wbl2/inv. All cross-block data uses these; read-only data stays L2-cached.
__device__ __forceinline__ float ld_dev(const float* p) {
    return __hip_atomic_load(p, __ATOMIC_RELAXED, __HIP_MEMORY_SCOPE_AGENT);
}
__device__ __forceinline__ void st_dev(float* p, float v) {
    __hip_atomic_store(p, v, __ATOMIC_RELAXED, __HIP_MEMORY_SCOPE_AGENT);
}

// Fully RELAXED device barrier. Ordering argument: __syncthreads drains each
// wave's vmcnt before s_barrier, and all cross-block stores are sc1
// write-through (ack'd at LLC when vmcnt retires), so the arrival RMW is
// ordered after data visibility without any wbl2. Consumers use sc1 bypass
// loads, so no inv is needed at exit. 16 leaves x 16 blocks + root + gen.
__device__ __forceinline__ void gbar(int* bar, int ibar) {
    __syncthreads();
    if (threadIdx.x == 0) {
        int g = blockIdx.x >> 4;
        int a = __hip_atomic_fetch_add(&bar[g * 32], 1, __ATOMIC_RELAXED,
                                       __HIP_MEMORY_SCOPE_AGENT);
        if (a == ibar * 16 + 15) {
            int r = __hip_atomic_fetch_add(&bar[640], 1, __ATOMIC_RELAXED,
                                           __HIP_MEMORY_SCOPE_AGENT);
            if (r == ibar * 16 + 15)
                __hip_atomic_store(&bar[704], ibar + 1, __ATOMIC_RELAXED,
                                   __HIP_MEMORY_SCOPE_AGENT);
        }
        while (__hip_atomic_load(&bar[704], __ATOMIC_RELAXED,
                                 __HIP_MEMORY_SCOPE_AGENT) <= ibar)
            __builtin_amdgcn_s_sleep(2);
    }
    __syncthreads();
}

// S0: zero state/barriers/denoms, token sequence, exp-shift = sum|v|.
__global__ void k_setup(const int* __restrict__ tgt, const float* __restrict__ vv,
                        float* zbase, int* bar, int* tok, float* shiftbuf) {
    int gid = blockIdx.x * 256 + threadIdx.x;
    // zero hxT(32768)+xo(16384)+cx(16384)+den(8192) = 73728 floats
    for (int i = gid; i < 73728; i += 96 * 256) zbase[i] = 0.f;
    if (gid < 1024) bar[gid] = 0;
    if (blockIdx.x == 0) {
        __shared__ int is64;
        if (threadIdx.x == 0) {
            int a = 1;
            for (int k = 0; k < 32; ++k) if (tgt[2 * k + 1] != 0) a = 0;
            is64 = a;
        }
        __syncthreads();
        int b = threadIdx.x;
        if (b < Bb) {
            int fin = 0;
            tok[0 * Bb + b] = 0;
            for (int s = 1; s < Ss; ++s) {
                int li = b * Tt + s;
                int nt = is64 ? tgt[2 * li] : tgt[li];
                if (nt == EOS_TOK) fin = 1;
                tok[s * Bb + b] = fin ? 0 : nt;
            }
        }
    }
    if (blockIdx.x == 1) {
        __shared__ float sred[256];
        int tid = threadIdx.x;
        sred[tid] = fabsf(vv[tid]) + fabsf(vv[tid + 256]);
        __syncthreads();
        for (int s = 128; s > 0; s >>= 1) {
            if (tid < s) sred[tid] += sred[tid + s];
            __syncthreads();
        }
        if (tid == 0) shiftbuf[0] = sred[0];
    }
}

// S1: gather embeddings for all steps into obuf slot fronts: [t][k][b]
__global__ void k_embx(const float* __restrict__ emb, const int* __restrict__ tok,
                       float* __restrict__ obuf) {
    int i = blockIdx.x * 256 + threadIdx.x;   // over 191*8192
    if (i < Ss * 8192) {
        int t = i >> 13, e = i & 8191;
        int k = e >> 5, b = e & 31;
        obuf[(size_t)(t + 1) * BD + e] = emb[(size_t)tok[t * 32 + b] * Ee + k];
    }
}

// S2: Wv[b,n,d] = sum_c enc[b,n,c] * W_v[c,d]
__global__ void k_wv(const float* __restrict__ enc, const float* __restrict__ Wv_w,
                     float* __restrict__ Wv) {
    int b = blockIdx.x / 24, nt = blockIdx.x % 24, n0 = nt * 16;
    __shared__ float encL[16 * 512];
    for (int i = 0; i < 32; ++i) {
        int e = threadIdx.x + i * 256;
        int ni = e >> 9, c = e & 511;
        encL[e] = enc[((b * Nn) + (n0 + ni)) * Cc + c];
    }
    __syncthreads();
    int d0 = threadIdx.x, d1 = threadIdx.x + 256;
    float a0[16], a1[16];
#pragma unroll
    for (int i = 0; i < 16; ++i) { a0[i] = 0.f; a1[i] = 0.f; }
    for (int c = 0; c < 512; ++c) {
        float w0 = Wv_w[c * Dd + d0], w1 = Wv_w[c * Dd + d1];
#pragma unroll
        for (int i = 0; i < 16; ++i) {
            float ev = encL[i * 512 + c];
            a0[i] += ev * w0; a1[i] += ev * w1;
        }
    }
#pragma unroll
    for (int i = 0; i < 16; ++i) {
        Wv[((b * Nn) + (n0 + i)) * Dd + d0] = a0[i];
        Wv[((b * Nn) + (n0 + i)) * Dd + d1] = a1[i];
    }
}

// Persistent decode: 256 blocks x 512 threads, weights LDS-resident,
// 4 fully-relaxed device barriers per step. Block bid owns dims {2bid, 2bid+1}.
__global__ __launch_bounds__(NTHR) void k_decode(
    const float* __restrict__ enc, const float* __restrict__ W_ih,
    const float* __restrict__ b_ih, const float* __restrict__ W_hh,
    const float* __restrict__ b_hh, const float* __restrict__ W_h,
    const float* __restrict__ vv, const float* __restrict__ W_c,
    const float* __restrict__ b_c, const float* __restrict__ Wv,
    const float* __restrict__ shiftbuf,
    float* __restrict__ hxT, float* __restrict__ xo, float* __restrict__ cx,
    float* __restrict__ den, float* __restrict__ q, float* __restrict__ ctxT,
    float* __restrict__ obuf, float* __restrict__ alpha_e, int* bar)
{
    __shared__ float Wg[1280 * 8];    // gates cols: [k][g*2+dd]   40960B
    __shared__ float Whx[512 * 2];    // W_h cols    [d][dd]        4096B
    __shared__ float Wc[1024 * 2];    // W_c cols    [k][dd]        8192B
    __shared__ float scratch[4096];   // phase-local               16384B

    const int tid = threadIdx.x, bid = blockIdx.x;
    const int lane = tid & 63;
    const int d0 = bid * 2;

    // ---- one-time weight staging into LDS (read-only, cached loads) ----
    for (int k = tid; k < 1280; k += NTHR) {
        const float* src = (k < 768) ? (W_ih + (size_t)k * 2048)
                                     : (W_hh + (size_t)(k - 768) * 2048);
#pragma unroll
        for (int g = 0; g < 4; ++g) {
            Wg[k * 8 + g * 2 + 0] = src[g * 512 + d0 + 0];
            Wg[k * 8 + g * 2 + 1] = src[g * 512 + d0 + 1];
        }
    }
    {
        int d = tid;  // NTHR == 512
        Whx[d * 2 + 0] = W_h[(size_t)d * 512 + d0 + 0];
        Whx[d * 2 + 1] = W_h[(size_t)d * 512 + d0 + 1];
    }
    for (int k = tid; k < 1024; k += NTHR) {
        Wc[k * 2 + 0] = W_c[(size_t)k * 512 + d0 + 0];
        Wc[k * 2 + 1] = W_c[(size_t)k * 512 + d0 + 1];
    }
    float v8[8];
#pragma unroll
    for (int i = 0; i < 8; ++i) v8[i] = vv[lane + i * 64];
    const float SHIFT = shiftbuf[0];
    float bsum0 = 0.f, bsum1 = 0.f, bsum2 = 0.f, bsum3 = 0.f, bcv = 0.f;
    if (tid < 64) {
        int dd = tid >> 5;
        int d = d0 + dd;
        bsum0 = b_ih[0 * 512 + d] + b_hh[0 * 512 + d];
        bsum1 = b_ih[1 * 512 + d] + b_hh[1 * 512 + d];
        bsum2 = b_ih[2 * 512 + d] + b_hh[2 * 512 + d];
        bsum3 = b_ih[3 * 512 + d] + b_hh[3 * 512 + d];
        bcv = b_c[d];
    }
    __syncthreads();

    int ib = 0;
    for (int t = 0; t < Ss; ++t) {
        const int rd = t & 1, wr = 1 - rd;
        float* hxT_rd = hxT + rd * 16384;
        float* hxT_wr = hxT + wr * 16384;

        // ---------- Phase A: gates (full K) + LSTM ----------
        {
            const float* embx_t = obuf + (size_t)(t + 1) * BD;  // [k][b], k<256 (cached)
            const float* xo2 = xo - 256 * 32;
            const float* hx2 = hxT_rd - 768 * 32;
            int b = tid & 31, ks = tid >> 5;       // 16 chunks of 80 k
            int k0 = ks * 80;
            float acc[8];
#pragma unroll
            for (int i = 0; i < 8; ++i) acc[i] = 0.f;
#pragma unroll 16
            for (int k = k0; k < k0 + 80; ++k) {
                float x;
                if (k < 256)       x = embx_t[k * 32 + b];
                else if (k < 768)  x = ld_dev(&xo2[k * 32 + b]);
                else               x = ld_dev(&hx2[k * 32 + b]);
                float4 wA = *(const float4*)&Wg[k * 8];
                float4 wB = *(const float4*)&Wg[k * 8 + 4];
                acc[0] += x * wA.x; acc[1] += x * wA.y; acc[2] += x * wA.z; acc[3] += x * wA.w;
                acc[4] += x * wB.x; acc[5] += x * wB.y; acc[6] += x * wB.z; acc[7] += x * wB.w;
            }
#pragma unroll
            for (int c = 0; c < 8; ++c) scratch[(ks * 8 + c) * 32 + b] = acc[c];
            __syncthreads();
            if (tid < 256) {
                int col = tid >> 5, b2 = tid & 31;
                float s = 0.f;
#pragma unroll
                for (int k2 = 0; k2 < 16; ++k2) s += scratch[(k2 * 8 + col) * 32 + b2];
                scratch[col * 32 + b2] = s;   // in-place: slot read only by this thread
            }
            __syncthreads();
            if (tid < 64) {
                int dd = tid >> 5, b2 = tid & 31;
                float gi = scratch[(0 * 2 + dd) * 32 + b2] + bsum0;
                float gf = scratch[(1 * 2 + dd) * 32 + b2] + bsum1;
                float gg = scratch[(2 * 2 + dd) * 32 + b2] + bsum2;
                float go = scratch[(3 * 2 + dd) * 32 + b2] + bsum3;
                int ci = (d0 + dd) * 32 + b2;
                float c = sigm_(gf) * cx[ci] + sigm_(gi) * tanh_(gg);   // cx block-private, cached
                cx[ci] = c;
                st_dev(&hxT_wr[ci], sigm_(go) * tanh_(c));
            }
        }
        gbar(bar, ib++);

        // ---------- Phase C: q = hx @ W_h (2 cols) + zero ctxT slice ----------
        {
            if (tid < 64)
                st_dev(&ctxT[bid * 64 + tid], 0.f);
            int b = tid & 31, dc = tid >> 5;      // 16 chunks of 32 d
            float a0 = 0.f, a1 = 0.f;
#pragma unroll 16
            for (int d = dc * 32; d < dc * 32 + 32; ++d) {
                float h = ld_dev(&hxT_wr[d * 32 + b]);
                a0 += h * Whx[d * 2 + 0];
                a1 += h * Whx[d * 2 + 1];
            }
            scratch[(dc * 2 + 0) * 32 + b] = a0;
            scratch[(dc * 2 + 1) * 32 + b] = a1;
            __syncthreads();
            if (tid < 64) {
                int jj = tid >> 5, b2 = tid & 31;
                float s = 0.f;
#pragma unroll
                for (int d2 = 0; d2 < 16; ++d2) s += scratch[(d2 * 2 + jj) * 32 + b2];
                st_dev(&q[b2 * 512 + d0 + jj], s);
            }
        }
        gbar(bar, ib++);

        // ---------- Phase DE: scores + exp(shifted) + ctx atomics ----------
        {
            float* esc = scratch;            // 48 e-values
            int b = bid >> 3, n0 = (bid & 7) * 48;
            int w = tid >> 6;
            float q8[8];
#pragma unroll
            for (int i = 0; i < 8; ++i) q8[i] = ld_dev(&q[b * 512 + lane + i * 64]);
#pragma unroll
            for (int r = 0; r < 6; ++r) {
                int n = n0 + w * 6 + r;
                const float* wv = Wv + ((size_t)(b * Nn + n)) * 512;   // read-only, L2-resident
                float s = 0.f;
#pragma unroll
                for (int i = 0; i < 8; ++i)
                    s += v8[i] * tanh_(q8[i] + wv[lane + i * 64]);
#pragma unroll
                for (int off = 32; off > 0; off >>= 1)
                    s += __shfl_down(s, off, 64);
                if (lane == 0) esc[w * 6 + r] = __expf(s - SHIFT);
            }
            __syncthreads();
            if (tid < 48)
                alpha_e[((size_t)b * Ss + t) * Nn + n0 + tid] = esc[tid];
            if (tid == 0) {
                float sd = 0.f;
                for (int i = 0; i < 48; ++i) sd += esc[i];
                atomicAdd(&den[t * 32 + b], sd);
            }
            int c = tid;
            float acc = 0.f;
#pragma unroll 8
            for (int i = 0; i < 48; ++i)
                acc += esc[i] * enc[((size_t)(b * Nn + n0 + i)) * 512 + c];  // read-only, L2
            atomicAdd(&ctxT[c * 32 + b], acc);
        }
        gbar(bar, ib++);

        // ---------- Phase F: o_t = tanh([hx|ctx/den] @ W_c + b_c) (2 cols) ----------
        {
            int b = tid & 31, kc = tid >> 5;      // 16 chunks of 64 k
            float dinv = 1.0f / ld_dev(&den[t * 32 + b]);
            float a0 = 0.f, a1 = 0.f;
            if (kc < 8) {
#pragma unroll 16
                for (int k = kc * 64; k < kc * 64 + 64; ++k) {
                    float x = ld_dev(&hxT_wr[k * 32 + b]);
                    a0 += x * Wc[k * 2 + 0]; a1 += x * Wc[k * 2 + 1];
                }
            } else {
#pragma unroll 16
                for (int k2 = (kc - 8) * 64; k2 < (kc - 8) * 64 + 64; ++k2) {
                    float x = ld_dev(&ctxT[k2 * 32 + b]);
                    a0 += x * Wc[(512 + k2) * 2 + 0]; a1 += x * Wc[(512 + k2) * 2 + 1];
                }
                a0 *= dinv; a1 *= dinv;   // normalize ctx half by softmax denom
            }
            scratch[(kc * 2 + 0) * 32 + b] = a0;
            scratch[(kc * 2 + 1) * 32 + b] = a1;
            __syncthreads();
            if (tid < 64) {
                int dd = tid >> 5, b2 = tid & 31;
                float s = bcv;
#pragma unroll
                for (int k2 = 0; k2 < 16; ++k2) s += scratch[(k2 * 2 + dd) * 32 + b2];
                float o = tanh_(s);
                st_dev(&xo[(d0 + dd) * 32 + b2], o);
                obuf[(size_t)(t + 1) * BD + b2 * 512 + d0 + dd] = o;  // read post-kernel only
            }
        }
        gbar(bar, ib++);
    }
}

// Deferred logits GEMM.
__global__ void k_logits(const float* __restrict__ obuf, const float* __restrict__ W_out,
                         const float* __restrict__ b_out, float* __restrict__ out_logits) {
    int b = blockIdx.x / 24, tt = blockIdx.x % 24;
    int t0 = tt * 8;
    int tmax = min(8, Ss - t0);
    __shared__ float oL[8 * 512];
    int tid = threadIdx.x;
    for (int i = 0; i < 16; ++i) {
        int e = tid + i * 256;
        int ti = e >> 9, d = e & 511;
        oL[e] = (ti < tmax) ? obuf[(size_t)(t0 + ti + 1) * BD + b * Dd + d] : 0.f;
    }
    __syncthreads();
    int v0 = tid, v1 = tid + 256, v2 = tid + 512;
    bool h2 = (v2 < Vv);
    int v2c = h2 ? v2 : 0;
    float acc[3][8];
#pragma unroll
    for (int s = 0; s < 3; ++s)
#pragma unroll
        for (int ti = 0; ti < 8; ++ti) acc[s][ti] = 0.f;
    for (int d = 0; d < 512; ++d) {
        float w0 = W_out[d * Vv + v0];
        float w1 = W_out[d * Vv + v1];
        float w2 = W_out[d * Vv + v2c];
#pragma unroll
        for (int ti = 0; ti < 8; ++ti) {
            float o = oL[ti * 512 + d];
            acc[0][ti] += o * w0; acc[1][ti] += o * w1; acc[2][ti] += o * w2;
        }
    }
    for (int ti = 0; ti < tmax; ++ti) {
        size_t base = (size_t)b * (Ss * Vv) + (size_t)(t0 + ti) * Vv;
        out_logits[base + v0] = acc[0][ti] + b_out[v0];
        out_logits[base + v1] = acc[1][ti] + b_out[v1];
        if (h2) out_logits[base + v2] = acc[2][ti] + b_out[v2];
    }
}

// Normalize alphas: alpha /= denom[b,t]
__global__ void k_anorm(float* __restrict__ alph, const float* __restrict__ den) {
    int i = blockIdx.x * 256 + threadIdx.x;
    if (i < ALPHA_SZ) {
        int bt = i / Nn;
        int t = bt % Ss, b = bt / Ss;
        alph[i] = alph[i] / den[t * 32 + b];
    }
}

extern "C" void kernel_launch(void* const* d_in, const int* in_sizes, int n_in,
                              void* d_out, int out_size, void* d_ws, size_t ws_size,
                              hipStream_t stream) {
    const float* enc   = (const float*)d_in[0];
    const int*   tgt   = (const int*)d_in[1];
    const float* emb   = (const float*)d_in[2];
    const float* W_ih  = (const float*)d_in[3];
    const float* b_ih  = (const float*)d_in[4];
    const float* W_hh  = (const float*)d_in[5];
    const float* b_hh  = (const float*)d_in[6];
    const float* W_h   = (const float*)d_in[7];
    const float* W_v   = (const float*)d_in[8];
    const float* vv    = (const float*)d_in[9];
    const float* W_c   = (const float*)d_in[10];
    const float* b_c   = (const float*)d_in[11];
    const float* W_out = (const float*)d_in[12];
    const float* b_out = (const float*)d_in[13];

    float* wsf   = (float*)d_ws;
    int*   tok   = (int*)d_ws;
    float* shiftb= wsf + OFF_SHIFT;
    float* Wv    = wsf + OFF_WV;
    float* hxT   = wsf + OFF_HXT;
    float* xo    = wsf + OFF_XO;
    float* cx    = wsf + OFF_CX;
    float* den   = wsf + OFF_DEN;
    float* q     = wsf + OFF_Q;
    float* ctxT  = wsf + OFF_CTX;
    float* obuf  = wsf + OFF_OBUF;
    int*   bar   = (int*)(wsf + OFF_BAR);

    float* out_logits = (float*)d_out;
    float* out_alphas = (float*)d_out + LOGITS_SZ;

    k_setup<<<96, 256, 0, stream>>>(tgt, vv, hxT, bar, tok, shiftb);
    k_embx<<<(Ss * 8192 + 255) / 256, 256, 0, stream>>>(emb, tok, obuf);
    k_wv<<<768, 256, 0, stream>>>(enc, W_v, Wv);
    k_decode<<<NBLK, NTHR, 0, stream>>>(enc, W_ih, b_ih, W_hh, b_hh, W_h, vv,
                                        W_c, b_c, Wv, shiftb,
                                        hxT, xo, cx, den, q, ctxT, obuf,
                                        out_alphas, bar);
    k_logits<<<768, 256, 0, stream>>>(obuf, W_out, b_out, out_logits);
    k_anorm<<<(ALPHA_SZ + 255) / 256, 256, 0, stream>>>(out_alphas, den);
}